// Round 11
// baseline (99.526 us; speedup 1.0000x reference)
//
#include <hip/hip_runtime.h>
#include <hip/hip_bf16.h>

typedef __attribute__((ext_vector_type(8))) short bf16x8;
typedef __attribute__((ext_vector_type(4))) float f32x4;

#define QSCALE 0.088388347648318447f   /* 1/sqrt(128) */

__device__ __forceinline__ unsigned short f2bf(float f) {
  __hip_bfloat16 h = __float2bfloat16(f);
  unsigned short u;
  __builtin_memcpy(&u, &h, 2);
  return u;
}
__device__ __forceinline__ float bf2f(unsigned short u) {
  unsigned int x = ((unsigned int)u) << 16;
  float f; __builtin_memcpy(&f, &x, 4);
  return f;
}

__device__ __forceinline__ void gload_lds16(void* lds, const void* g) {
  __builtin_amdgcn_global_load_lds(
      (const __attribute__((address_space(1))) unsigned int*)g,
      (__attribute__((address_space(3))) unsigned int*)lds, 16, 0, 0);
}

// ---- build W^T (384 x 1024) bf16, Q part pre-scaled by 1/sqrt(dk) ----
__global__ __launch_bounds__(256) void cvt_w(const float* __restrict__ Wq,
                                             const float* __restrict__ Wk,
                                             const float* __restrict__ Wv,
                                             unsigned short* __restrict__ Wt) {
  int idx = blockIdx.x * 256 + threadIdx.x;   // [0, 393216)
  int n = idx >> 10, d = idx & 1023;
  const float* W = (n < 128) ? Wq : (n < 256 ? Wk : Wv);
  float v = W[d * 128 + (n & 127)];
  if (n < 128) v *= QSCALE;
  Wt[idx] = f2bf(v);
}

// ---- fused QKV projection: [8192x1024] @ [1024x384], 64x64 tiles ----
// A (X) read directly as fp32, converted in-register, staged to LDS (kills
// the separate cvt_x pass: saves a 96MB HBM round-trip). B via global_load_lds.
__global__ __launch_bounds__(256) void proj_gemm(
    const float* __restrict__ X, const unsigned short* __restrict__ Wt,
    const float* __restrict__ bq, const float* __restrict__ bk, const float* __restrict__ bv,
    unsigned short* __restrict__ Qb, unsigned short* __restrict__ Kb,
    unsigned short* __restrict__ Vt) {
  __shared__ unsigned short sA[64 * 64];
  __shared__ unsigned short sB[64 * 64];
  const int nt = blockIdx.x % 6;
  const int mt = blockIdx.x / 6;
  const int m0 = mt * 64;
  const int n0 = nt * 64;
  const int tid = threadIdx.x;
  const int lane = tid & 63;
  const int w = tid >> 6;
  const int r = lane & 15, g = lane >> 4;
  const int wm = (w >> 1) * 32, wn = (w & 1) * 32;

  f32x4 acc[2][2];
  #pragma unroll
  for (int mi = 0; mi < 2; ++mi)
    #pragma unroll
    for (int ni = 0; ni < 2; ++ni)
      acc[mi][ni] = (f32x4){0.f, 0.f, 0.f, 0.f};

  const char* Bb = (const char*)Wt;
  char* sBb = (char*)sB;

  for (int k0 = 0; k0 < 1024; k0 += 64) {
    // stage A: 64x64 fp32 -> bf16 via registers (16 floats/thread)
    #pragma unroll
    for (int it = 0; it < 4; ++it) {
      const int f = it * 1024 + tid * 4;          // float index in 64x64 tile
      const int row = f >> 6, k = f & 63;
      const float4 v = *reinterpret_cast<const float4*>(
          X + (size_t)(m0 + row) * 1024 + k0 + k);
      ushort4 o4;
      o4.x = f2bf(v.x); o4.y = f2bf(v.y); o4.z = f2bf(v.z); o4.w = f2bf(v.w);
      *reinterpret_cast<ushort4*>(&sA[row * 64 + k]) = o4;
    }
    // stage B: bf16 via global_load_lds (16B/thread x2)
    #pragma unroll
    for (int j = 0; j < 2; ++j) {
      int fb = j * 4096 + tid * 16;
      int row = fb >> 7, colb = fb & 127;
      gload_lds16(sBb + fb, Bb + ((size_t)(n0 + row) * 1024 + k0) * 2 + colb);
    }
    __syncthreads();
    #pragma unroll
    for (int kk = 0; kk < 2; ++kk) {
      bf16x8 af[2], bfr[2];
      #pragma unroll
      for (int mi = 0; mi < 2; ++mi)
        af[mi] = *reinterpret_cast<const bf16x8*>(sA + (wm + mi * 16 + r) * 64 + kk * 32 + g * 8);
      #pragma unroll
      for (int ni = 0; ni < 2; ++ni)
        bfr[ni] = *reinterpret_cast<const bf16x8*>(sB + (wn + ni * 16 + r) * 64 + kk * 32 + g * 8);
      #pragma unroll
      for (int mi = 0; mi < 2; ++mi)
        #pragma unroll
        for (int ni = 0; ni < 2; ++ni)
          acc[mi][ni] = __builtin_amdgcn_mfma_f32_16x16x32_bf16(af[mi], bfr[ni], acc[mi][ni], 0, 0, 0);
    }
    __syncthreads();
  }

  const float* bias = (nt < 2) ? bq : (nt < 4 ? bk : bv);
  const float bsc = (nt < 2) ? QSCALE : 1.0f;
  #pragma unroll
  for (int mi = 0; mi < 2; ++mi) {
    #pragma unroll
    for (int ni = 0; ni < 2; ++ni) {
      const int colg = n0 + wn + ni * 16 + r;      // [0,384)
      const int colm = colg & 127;
      const float bias_v = bias[colm] * bsc;
      #pragma unroll
      for (int e = 0; e < 4; ++e) {
        const int row = m0 + wm + mi * 16 + g * 4 + e;   // [0,8192)
        const unsigned short hh = f2bf(acc[mi][ni][e] + bias_v);
        if (nt < 2) Qb[(size_t)row * 128 + colm] = hh;
        else if (nt < 4) Kb[(size_t)row * 128 + colm] = hh;
        else {
          const int bb = row >> 11, s = row & 2047;
          Vt[((size_t)bb * 128 + colm) * 2048 + s] = hh;
        }
      }
    }
  }
}

// ---- flash attention, inverted (strictly-upper) mask, FIXED-MAX softmax ----
// 2-tile software pipeline: two independent QK->exp->transpose chains share a
// single lgkmcnt(0) drain, then 16 PV MFMAs -> 2x ILP per wave, half the
// drains. Pairing: t=p and 127-p sum to 65 tiles; bid&7 = (b,h) XCD decode.
// Partials additive (fixed-max exp); `combine` merges the two halves.
__global__ __launch_bounds__(512, 4) void attn(
    const unsigned short* __restrict__ Qb, const unsigned short* __restrict__ Kb,
    const unsigned short* __restrict__ Vt,
    float* __restrict__ po, float* __restrict__ pl) {
  __shared__ float o_lds[8][16][128];   // 64KB partials; first 2KB/wave doubles as pbuf
  __shared__ float l_lds[8][16];
  const int tid = threadIdx.x;
  const int lane = tid & 63;
  const int w = tid >> 6;
  const int r = lane & 15, g = lane >> 4;
  const int x = blockIdx.x & 7;
  const int b = x >> 1;
  const int h = x & 1;
  const int p = blockIdx.x >> 3;            // [0,64)

  const unsigned short* K = Kb + (size_t)b * 2048 * 128;
  const unsigned short* V = Vt + (size_t)b * 128 * 2048;
  unsigned short* pbuf = (unsigned short*)&o_lds[w][0][0];  // per-wave 2KB scratch

  for (int phase = 0; phase < 2; ++phase) {
    const int t = phase ? (127 - p) : p;
    const int q0 = t * 16;
    const int sb = q0 & ~31;
    const int ntiles = (2048 - sb) >> 5;

    const unsigned short* Q = Qb + ((size_t)(b * 2048 + q0)) * 128;
    bf16x8 qf[4];
    #pragma unroll
    for (int kk = 0; kk < 4; ++kk)
      qf[kk] = *reinterpret_cast<const bf16x8*>(Q + r * 128 + kk * 32 + g * 8);

    f32x4 o[8];
    #pragma unroll
    for (int ni = 0; ni < 8; ++ni) o[ni] = (f32x4){0.f, 0.f, 0.f, 0.f};
    float l[4];
    #pragma unroll
    for (int e = 0; e < 4; ++e) l[e] = 0.f;

    int j = h + 2 * w;
    // ---- paired iterations: tiles j and j+16 in flight together ----
    for (; j + 16 < ntiles; j += 32) {
      const int s0a = sb + j * 32;
      const int s0b = s0a + 512;            // (j+16)*32
      f32x4 sta[2], stb[2];
      #pragma unroll
      for (int sj = 0; sj < 2; ++sj) {
        f32x4 a = (f32x4){0.f, 0.f, 0.f, 0.f};
        f32x4 bacc = (f32x4){0.f, 0.f, 0.f, 0.f};
        #pragma unroll
        for (int kk = 0; kk < 4; ++kk) {
          const bf16x8 kfa = *reinterpret_cast<const bf16x8*>(
              K + (size_t)(s0a + sj * 16 + r) * 128 + kk * 32 + g * 8);
          const bf16x8 kfb = *reinterpret_cast<const bf16x8*>(
              K + (size_t)(s0b + sj * 16 + r) * 128 + kk * 32 + g * 8);
          a = __builtin_amdgcn_mfma_f32_16x16x32_bf16(qf[kk], kfa, a, 0, 0, 0);
          bacc = __builtin_amdgcn_mfma_f32_16x16x32_bf16(qf[kk], kfb, bacc, 0, 0, 0);
        }
        sta[sj] = a;
        stb[sj] = bacc;
      }
      // mask (valid iff s > q) + exp(fixed max 0)
      #pragma unroll
      for (int sj = 0; sj < 2; ++sj) {
        const int sa = s0a + sj * 16 + r;
        const int sbv = s0b + sj * 16 + r;
        #pragma unroll
        for (int e = 0; e < 4; ++e) {
          const int q = q0 + g * 4 + e;
          sta[sj][e] = (sa <= q) ? 0.f : __expf(sta[sj][e]);
          stb[sj][e] = (sbv <= q) ? 0.f : __expf(stb[sj][e]);
        }
      }
      // row sums
      float ra[4], rb[4];
      #pragma unroll
      for (int e = 0; e < 4; ++e) { ra[e] = sta[0][e] + sta[1][e]; rb[e] = stb[0][e] + stb[1][e]; }
      #pragma unroll
      for (int off = 1; off < 16; off <<= 1)
        #pragma unroll
        for (int e = 0; e < 4; ++e) {
          ra[e] += __shfl_xor(ra[e], off, 64);
          rb[e] += __shfl_xor(rb[e], off, 64);
        }
      #pragma unroll
      for (int e = 0; e < 4; ++e) l[e] += ra[e] + rb[e];

      // transpose both P tiles through LDS with ONE drain
      #pragma unroll
      for (int sj = 0; sj < 2; ++sj)
        #pragma unroll
        for (int e = 0; e < 4; ++e) {
          pbuf[(g * 4 + e) * 32 + sj * 16 + r] = f2bf(sta[sj][e]);
          pbuf[512 + (g * 4 + e) * 32 + sj * 16 + r] = f2bf(stb[sj][e]);
        }
      asm volatile("s_waitcnt lgkmcnt(0)" ::: "memory");
      __builtin_amdgcn_sched_barrier(0);
      const bf16x8 paa = *reinterpret_cast<const bf16x8*>(&pbuf[r * 32 + g * 8]);
      const bf16x8 pab = *reinterpret_cast<const bf16x8*>(&pbuf[512 + r * 32 + g * 8]);

      // accumulate P.V for both tiles
      #pragma unroll
      for (int ni = 0; ni < 8; ++ni) {
        const bf16x8 vfa = *reinterpret_cast<const bf16x8*>(
            V + (size_t)(ni * 16 + r) * 2048 + s0a + g * 8);
        const bf16x8 vfb = *reinterpret_cast<const bf16x8*>(
            V + (size_t)(ni * 16 + r) * 2048 + s0b + g * 8);
        o[ni] = __builtin_amdgcn_mfma_f32_16x16x32_bf16(paa, vfa, o[ni], 0, 0, 0);
        o[ni] = __builtin_amdgcn_mfma_f32_16x16x32_bf16(pab, vfb, o[ni], 0, 0, 0);
      }
    }
    // ---- odd tail: single tile ----
    if (j < ntiles) {
      const int s0 = sb + j * 32;
      f32x4 st[2];
      #pragma unroll
      for (int sj = 0; sj < 2; ++sj) {
        f32x4 a = (f32x4){0.f, 0.f, 0.f, 0.f};
        #pragma unroll
        for (int kk = 0; kk < 4; ++kk) {
          const bf16x8 kf = *reinterpret_cast<const bf16x8*>(
              K + (size_t)(s0 + sj * 16 + r) * 128 + kk * 32 + g * 8);
          a = __builtin_amdgcn_mfma_f32_16x16x32_bf16(qf[kk], kf, a, 0, 0, 0);
        }
        st[sj] = a;
      }
      #pragma unroll
      for (int sj = 0; sj < 2; ++sj) {
        const int s = s0 + sj * 16 + r;
        #pragma unroll
        for (int e = 0; e < 4; ++e) {
          const int q = q0 + g * 4 + e;
          st[sj][e] = (s <= q) ? 0.f : __expf(st[sj][e]);
        }
      }
      float rsum[4];
      #pragma unroll
      for (int e = 0; e < 4; ++e) rsum[e] = st[0][e] + st[1][e];
      #pragma unroll
      for (int off = 1; off < 16; off <<= 1)
        #pragma unroll
        for (int e = 0; e < 4; ++e)
          rsum[e] += __shfl_xor(rsum[e], off, 64);
      #pragma unroll
      for (int e = 0; e < 4; ++e) l[e] += rsum[e];

      #pragma unroll
      for (int sj = 0; sj < 2; ++sj)
        #pragma unroll
        for (int e = 0; e < 4; ++e)
          pbuf[(g * 4 + e) * 32 + sj * 16 + r] = f2bf(st[sj][e]);
      asm volatile("s_waitcnt lgkmcnt(0)" ::: "memory");
      __builtin_amdgcn_sched_barrier(0);
      const bf16x8 pa = *reinterpret_cast<const bf16x8*>(&pbuf[r * 32 + g * 8]);

      #pragma unroll
      for (int ni = 0; ni < 8; ++ni) {
        const bf16x8 vf = *reinterpret_cast<const bf16x8*>(
            V + (size_t)(ni * 16 + r) * 2048 + s0 + g * 8);
        o[ni] = __builtin_amdgcn_mfma_f32_16x16x32_bf16(pa, vf, o[ni], 0, 0, 0);
      }
    }

    // ---- stash per-wave partials ----
    if (r == 0) {
      #pragma unroll
      for (int e = 0; e < 4; ++e) l_lds[w][g * 4 + e] = l[e];
    }
    #pragma unroll
    for (int ni = 0; ni < 8; ++ni)
      #pragma unroll
      for (int e = 0; e < 4; ++e) {
        const int row = g * 4 + e;
        const int col = ni * 16 + r;
        o_lds[w][row][col ^ ((row >> 2) << 3)] = o[ni][e];   // XOR-swizzle
      }
    __syncthreads();

    // ---- block-level additive reduce; write partial to workspace ----
    const int col = tid & 127;
    const size_t tile2 = ((size_t)(b * 128 + t)) * 2 + h;
    #pragma unroll
    for (int rr = 0; rr < 4; ++rr) {
      const int row = (tid >> 7) * 4 + rr;
      float val = 0.f;
      #pragma unroll
      for (int ww = 0; ww < 8; ++ww)
        val += o_lds[ww][row][col ^ ((row >> 2) << 3)];
      po[tile2 * 2048 + row * 128 + col] = val;
      if (col == 0) {
        float lt = 0.f;
        #pragma unroll
        for (int ww = 0; ww < 8; ++ww) lt += l_lds[ww][row];
        pl[tile2 * 16 + row] = lt;
      }
    }
    __syncthreads();   // protect o_lds/l_lds before next phase reuses them
  }
}

// ---- merge the two half-partials: out = (o0+o1)/(l0+l1) ----
__global__ __launch_bounds__(256) void combine(const float* __restrict__ po,
                                               const float* __restrict__ pl,
                                               float* __restrict__ out) {
  const int idx = blockIdx.x * 256 + threadIdx.x;   // [0, 1048576)
  const int col = idx & 127;
  const int gq = idx >> 7;          // [0, 8192)
  const int b = gq >> 11, q = gq & 2047;
  const int t = q >> 4, row = q & 15;
  const size_t tile2 = ((size_t)(b * 128 + t)) * 2;
  const float o = po[tile2 * 2048 + row * 128 + col] +
                  po[(tile2 + 1) * 2048 + row * 128 + col];
  const float l = pl[tile2 * 16 + row] + pl[(tile2 + 1) * 16 + row];
  out[idx] = (l > 0.f) ? o / l : 0.f;
}

// ---- last row (q = S-1): reference's score-1e9 rounds all-equal -> uniform softmax -> mean(V) ----
__global__ __launch_bounds__(64) void lastrow(const unsigned short* __restrict__ Vt,
                                              float* __restrict__ out) {
  const int b = blockIdx.x >> 7;
  const int dk = blockIdx.x & 127;
  const unsigned short* row = Vt + (size_t)(b * 128 + dk) * 2048;
  float s = 0.f;
  for (int i = threadIdx.x; i < 2048; i += 64) s += bf2f(row[i]);
  #pragma unroll
  for (int off = 32; off > 0; off >>= 1) s += __shfl_down(s, off, 64);
  if (threadIdx.x == 0) out[(size_t)(b * 2048 + 2047) * 128 + dk] = s * (1.0f / 2048.0f);
}

extern "C" void kernel_launch(void* const* d_in, const int* in_sizes, int n_in,
                              void* d_out, int out_size, void* d_ws, size_t ws_size,
                              hipStream_t stream) {
  const float* x  = (const float*)d_in[0];
  const float* Wq = (const float*)d_in[1];
  const float* bq = (const float*)d_in[2];
  const float* Wk = (const float*)d_in[3];
  const float* bk = (const float*)d_in[4];
  const float* Wv = (const float*)d_in[5];
  const float* bv = (const float*)d_in[6];
  float* out = (float*)d_out;
  char* ws = (char*)d_ws;
  // workspace layout (bytes):
  //   [0,8MB): po | [8,8.07MB): pl | [16,17MB): Wt | [17,19): Qb
  //   [19,21): Kb | [21,23): Vt
  float* po = (float*)(ws);
  float* pl = (float*)(ws + (size_t)(8u << 20));
  unsigned short* Wt = (unsigned short*)(ws + (size_t)(16u << 20));
  unsigned short* Qb = (unsigned short*)(ws + (size_t)(17u << 20));
  unsigned short* Kb = (unsigned short*)(ws + (size_t)(19u << 20));
  unsigned short* Vt = (unsigned short*)(ws + (size_t)(21u << 20));

  hipLaunchKernelGGL(cvt_w, dim3(1536), dim3(256), 0, stream, Wq, Wk, Wv, Wt);
  hipLaunchKernelGGL(proj_gemm, dim3(768), dim3(256), 0, stream,
                     x, Wt, bq, bk, bv, Qb, Kb, Vt);
  hipLaunchKernelGGL(attn, dim3(512), dim3(512), 0, stream, Qb, Kb, Vt, po, pl);
  hipLaunchKernelGGL(combine, dim3(4096), dim3(256), 0, stream, po, pl, out);
  hipLaunchKernelGGL(lastrow, dim3(512), dim3(64), 0, stream, Vt, out);
}

// Round 14
// 89.055 us; speedup vs baseline: 1.1176x; 1.1176x over previous
//
#include <hip/hip_runtime.h>
#include <hip/hip_bf16.h>

typedef __attribute__((ext_vector_type(8))) short bf16x8;
typedef __attribute__((ext_vector_type(4))) float f32x4;

#define QSCALE 0.088388347648318447f   /* 1/sqrt(128) */

__device__ __forceinline__ unsigned short f2bf(float f) {
  __hip_bfloat16 h = __float2bfloat16(f);
  unsigned short u;
  __builtin_memcpy(&u, &h, 2);
  return u;
}
__device__ __forceinline__ float bf2f(unsigned short u) {
  unsigned int x = ((unsigned int)u) << 16;
  float f; __builtin_memcpy(&f, &x, 4);
  return f;
}

__device__ __forceinline__ void gload_lds16(void* lds, const void* g) {
  __builtin_amdgcn_global_load_lds(
      (const __attribute__((address_space(1))) unsigned int*)g,
      (__attribute__((address_space(3))) unsigned int*)lds, 16, 0, 0);
}

// ---- convert inputs fp32 -> bf16 (8 elem/thread) ----
__global__ __launch_bounds__(256) void cvt_x(const float* __restrict__ x,
                                             unsigned short* __restrict__ xb) {
  int i = (blockIdx.x * 256 + threadIdx.x) * 8;
  float4 v0 = *reinterpret_cast<const float4*>(x + i);
  float4 v1 = *reinterpret_cast<const float4*>(x + i + 4);
  ushort4 o0, o1;
  o0.x = f2bf(v0.x); o0.y = f2bf(v0.y); o0.z = f2bf(v0.z); o0.w = f2bf(v0.w);
  o1.x = f2bf(v1.x); o1.y = f2bf(v1.y); o1.z = f2bf(v1.z); o1.w = f2bf(v1.w);
  *reinterpret_cast<ushort4*>(xb + i) = o0;
  *reinterpret_cast<ushort4*>(xb + i + 4) = o1;
}

// ---- build W^T (384 x 1024) bf16, Q part pre-scaled by 1/sqrt(dk) ----
__global__ __launch_bounds__(256) void cvt_w(const float* __restrict__ Wq,
                                             const float* __restrict__ Wk,
                                             const float* __restrict__ Wv,
                                             unsigned short* __restrict__ Wt) {
  int idx = blockIdx.x * 256 + threadIdx.x;   // [0, 393216)
  int n = idx >> 10, d = idx & 1023;
  const float* W = (n < 128) ? Wq : (n < 256 ? Wk : Wv);
  float v = W[d * 128 + (n & 127)];
  if (n < 128) v *= QSCALE;
  Wt[idx] = f2bf(v);
}

// ---- fused QKV projection: [8192x1024] @ [1024x384], 64x64 tiles ----
// A and B both bf16, staged via global_load_lds (async, zero bank conflicts).
__global__ __launch_bounds__(256) void proj_gemm(
    const unsigned short* __restrict__ Xb, const unsigned short* __restrict__ Wt,
    const float* __restrict__ bq, const float* __restrict__ bk, const float* __restrict__ bv,
    unsigned short* __restrict__ Qb, unsigned short* __restrict__ Kb,
    unsigned short* __restrict__ Vt) {
  __shared__ unsigned short sA[64 * 64];
  __shared__ unsigned short sB[64 * 64];
  const int nt = blockIdx.x % 6;
  const int mt = blockIdx.x / 6;
  const int m0 = mt * 64;
  const int n0 = nt * 64;
  const int tid = threadIdx.x;
  const int lane = tid & 63;
  const int w = tid >> 6;
  const int r = lane & 15, g = lane >> 4;
  const int wm = (w >> 1) * 32, wn = (w & 1) * 32;

  f32x4 acc[2][2];
  #pragma unroll
  for (int mi = 0; mi < 2; ++mi)
    #pragma unroll
    for (int ni = 0; ni < 2; ++ni)
      acc[mi][ni] = (f32x4){0.f, 0.f, 0.f, 0.f};

  const char* Ab = (const char*)Xb;
  const char* Bb = (const char*)Wt;
  char* sAb = (char*)sA;
  char* sBb = (char*)sB;

  for (int k0 = 0; k0 < 1024; k0 += 64) {
    #pragma unroll
    for (int j = 0; j < 2; ++j) {
      int f = j * 4096 + tid * 16;   // byte offset within 8KB tile
      int row = f >> 7;              // 128 bytes per row (64 bf16)
      int colb = f & 127;
      gload_lds16(sAb + f, Ab + ((size_t)(m0 + row) * 1024 + k0) * 2 + colb);
      gload_lds16(sBb + f, Bb + ((size_t)(n0 + row) * 1024 + k0) * 2 + colb);
    }
    __syncthreads();
    #pragma unroll
    for (int kk = 0; kk < 2; ++kk) {
      bf16x8 af[2], bfr[2];
      #pragma unroll
      for (int mi = 0; mi < 2; ++mi)
        af[mi] = *reinterpret_cast<const bf16x8*>(sA + (wm + mi * 16 + r) * 64 + kk * 32 + g * 8);
      #pragma unroll
      for (int ni = 0; ni < 2; ++ni)
        bfr[ni] = *reinterpret_cast<const bf16x8*>(sB + (wn + ni * 16 + r) * 64 + kk * 32 + g * 8);
      #pragma unroll
      for (int mi = 0; mi < 2; ++mi)
        #pragma unroll
        for (int ni = 0; ni < 2; ++ni)
          acc[mi][ni] = __builtin_amdgcn_mfma_f32_16x16x32_bf16(af[mi], bfr[ni], acc[mi][ni], 0, 0, 0);
    }
    __syncthreads();
  }

  const float* bias = (nt < 2) ? bq : (nt < 4 ? bk : bv);
  const float bsc = (nt < 2) ? QSCALE : 1.0f;
  #pragma unroll
  for (int mi = 0; mi < 2; ++mi) {
    #pragma unroll
    for (int ni = 0; ni < 2; ++ni) {
      const int colg = n0 + wn + ni * 16 + r;      // [0,384)
      const int colm = colg & 127;
      const float bias_v = bias[colm] * bsc;
      #pragma unroll
      for (int e = 0; e < 4; ++e) {
        const int row = m0 + wm + mi * 16 + g * 4 + e;   // [0,8192)
        const unsigned short hh = f2bf(acc[mi][ni][e] + bias_v);
        if (nt < 2) Qb[(size_t)row * 128 + colm] = hh;
        else if (nt < 4) Kb[(size_t)row * 128 + colm] = hh;
        else {
          const int bb = row >> 11, s = row & 2047;
          Vt[((size_t)bb * 128 + colm) * 2048 + s] = hh;
        }
      }
    }
  }
}

// ---- flash attention, inverted (strictly-upper) mask, FIXED-MAX softmax ----
// 2-tile software pipeline: two independent QK->exp->transpose chains share a
// single lgkmcnt(0) drain, then 16 PV MFMAs -> 2x ILP per wave, half the
// drains. Pairing: t=p and 127-p sum to 65 tiles; bid&7 = (b,h) XCD decode.
// Partials additive (fixed-max exp); `combine` merges the two halves.
__global__ __launch_bounds__(512, 4) void attn(
    const unsigned short* __restrict__ Qb, const unsigned short* __restrict__ Kb,
    const unsigned short* __restrict__ Vt,
    float* __restrict__ po, float* __restrict__ pl) {
  __shared__ float o_lds[8][16][128];   // 64KB partials; first 2KB/wave doubles as pbuf
  __shared__ float l_lds[8][16];
  const int tid = threadIdx.x;
  const int lane = tid & 63;
  const int w = tid >> 6;
  const int r = lane & 15, g = lane >> 4;
  const int x = blockIdx.x & 7;
  const int b = x >> 1;
  const int h = x & 1;
  const int p = blockIdx.x >> 3;            // [0,64)

  const unsigned short* K = Kb + (size_t)b * 2048 * 128;
  const unsigned short* V = Vt + (size_t)b * 128 * 2048;
  unsigned short* pbuf = (unsigned short*)&o_lds[w][0][0];  // per-wave 2KB scratch

  for (int phase = 0; phase < 2; ++phase) {
    const int t = phase ? (127 - p) : p;
    const int q0 = t * 16;
    const int sb = q0 & ~31;
    const int ntiles = (2048 - sb) >> 5;

    const unsigned short* Q = Qb + ((size_t)(b * 2048 + q0)) * 128;
    bf16x8 qf[4];
    #pragma unroll
    for (int kk = 0; kk < 4; ++kk)
      qf[kk] = *reinterpret_cast<const bf16x8*>(Q + r * 128 + kk * 32 + g * 8);

    f32x4 o[8];
    #pragma unroll
    for (int ni = 0; ni < 8; ++ni) o[ni] = (f32x4){0.f, 0.f, 0.f, 0.f};
    float l[4];
    #pragma unroll
    for (int e = 0; e < 4; ++e) l[e] = 0.f;

    int j = h + 2 * w;
    // ---- paired iterations: tiles j and j+16 in flight together ----
    for (; j + 16 < ntiles; j += 32) {
      const int s0a = sb + j * 32;
      const int s0b = s0a + 512;            // (j+16)*32
      f32x4 sta[2], stb[2];
      #pragma unroll
      for (int sj = 0; sj < 2; ++sj) {
        f32x4 a = (f32x4){0.f, 0.f, 0.f, 0.f};
        f32x4 bacc = (f32x4){0.f, 0.f, 0.f, 0.f};
        #pragma unroll
        for (int kk = 0; kk < 4; ++kk) {
          const bf16x8 kfa = *reinterpret_cast<const bf16x8*>(
              K + (size_t)(s0a + sj * 16 + r) * 128 + kk * 32 + g * 8);
          const bf16x8 kfb = *reinterpret_cast<const bf16x8*>(
              K + (size_t)(s0b + sj * 16 + r) * 128 + kk * 32 + g * 8);
          a = __builtin_amdgcn_mfma_f32_16x16x32_bf16(qf[kk], kfa, a, 0, 0, 0);
          bacc = __builtin_amdgcn_mfma_f32_16x16x32_bf16(qf[kk], kfb, bacc, 0, 0, 0);
        }
        sta[sj] = a;
        stb[sj] = bacc;
      }
      // mask (valid iff s > q) + exp(fixed max 0)
      #pragma unroll
      for (int sj = 0; sj < 2; ++sj) {
        const int sa = s0a + sj * 16 + r;
        const int sbv = s0b + sj * 16 + r;
        #pragma unroll
        for (int e = 0; e < 4; ++e) {
          const int q = q0 + g * 4 + e;
          sta[sj][e] = (sa <= q) ? 0.f : __expf(sta[sj][e]);
          stb[sj][e] = (sbv <= q) ? 0.f : __expf(stb[sj][e]);
        }
      }
      // row sums
      float ra[4], rb[4];
      #pragma unroll
      for (int e = 0; e < 4; ++e) { ra[e] = sta[0][e] + sta[1][e]; rb[e] = stb[0][e] + stb[1][e]; }
      #pragma unroll
      for (int off = 1; off < 16; off <<= 1)
        #pragma unroll
        for (int e = 0; e < 4; ++e) {
          ra[e] += __shfl_xor(ra[e], off, 64);
          rb[e] += __shfl_xor(rb[e], off, 64);
        }
      #pragma unroll
      for (int e = 0; e < 4; ++e) l[e] += ra[e] + rb[e];

      // transpose both P tiles through LDS with ONE drain
      #pragma unroll
      for (int sj = 0; sj < 2; ++sj)
        #pragma unroll
        for (int e = 0; e < 4; ++e) {
          pbuf[(g * 4 + e) * 32 + sj * 16 + r] = f2bf(sta[sj][e]);
          pbuf[512 + (g * 4 + e) * 32 + sj * 16 + r] = f2bf(stb[sj][e]);
        }
      asm volatile("s_waitcnt lgkmcnt(0)" ::: "memory");
      __builtin_amdgcn_sched_barrier(0);
      const bf16x8 paa = *reinterpret_cast<const bf16x8*>(&pbuf[r * 32 + g * 8]);
      const bf16x8 pab = *reinterpret_cast<const bf16x8*>(&pbuf[512 + r * 32 + g * 8]);

      // accumulate P.V for both tiles
      #pragma unroll
      for (int ni = 0; ni < 8; ++ni) {
        const bf16x8 vfa = *reinterpret_cast<const bf16x8*>(
            V + (size_t)(ni * 16 + r) * 2048 + s0a + g * 8);
        const bf16x8 vfb = *reinterpret_cast<const bf16x8*>(
            V + (size_t)(ni * 16 + r) * 2048 + s0b + g * 8);
        o[ni] = __builtin_amdgcn_mfma_f32_16x16x32_bf16(paa, vfa, o[ni], 0, 0, 0);
        o[ni] = __builtin_amdgcn_mfma_f32_16x16x32_bf16(pab, vfb, o[ni], 0, 0, 0);
      }
    }
    // ---- odd tail: single tile ----
    if (j < ntiles) {
      const int s0 = sb + j * 32;
      f32x4 st[2];
      #pragma unroll
      for (int sj = 0; sj < 2; ++sj) {
        f32x4 a = (f32x4){0.f, 0.f, 0.f, 0.f};
        #pragma unroll
        for (int kk = 0; kk < 4; ++kk) {
          const bf16x8 kf = *reinterpret_cast<const bf16x8*>(
              K + (size_t)(s0 + sj * 16 + r) * 128 + kk * 32 + g * 8);
          a = __builtin_amdgcn_mfma_f32_16x16x32_bf16(qf[kk], kf, a, 0, 0, 0);
        }
        st[sj] = a;
      }
      #pragma unroll
      for (int sj = 0; sj < 2; ++sj) {
        const int s = s0 + sj * 16 + r;
        #pragma unroll
        for (int e = 0; e < 4; ++e) {
          const int q = q0 + g * 4 + e;
          st[sj][e] = (s <= q) ? 0.f : __expf(st[sj][e]);
        }
      }
      float rsum[4];
      #pragma unroll
      for (int e = 0; e < 4; ++e) rsum[e] = st[0][e] + st[1][e];
      #pragma unroll
      for (int off = 1; off < 16; off <<= 1)
        #pragma unroll
        for (int e = 0; e < 4; ++e)
          rsum[e] += __shfl_xor(rsum[e], off, 64);
      #pragma unroll
      for (int e = 0; e < 4; ++e) l[e] += rsum[e];

      #pragma unroll
      for (int sj = 0; sj < 2; ++sj)
        #pragma unroll
        for (int e = 0; e < 4; ++e)
          pbuf[(g * 4 + e) * 32 + sj * 16 + r] = f2bf(st[sj][e]);
      asm volatile("s_waitcnt lgkmcnt(0)" ::: "memory");
      __builtin_amdgcn_sched_barrier(0);
      const bf16x8 pa = *reinterpret_cast<const bf16x8*>(&pbuf[r * 32 + g * 8]);

      #pragma unroll
      for (int ni = 0; ni < 8; ++ni) {
        const bf16x8 vf = *reinterpret_cast<const bf16x8*>(
            V + (size_t)(ni * 16 + r) * 2048 + s0 + g * 8);
        o[ni] = __builtin_amdgcn_mfma_f32_16x16x32_bf16(pa, vf, o[ni], 0, 0, 0);
      }
    }

    // ---- stash per-wave partials ----
    if (r == 0) {
      #pragma unroll
      for (int e = 0; e < 4; ++e) l_lds[w][g * 4 + e] = l[e];
    }
    #pragma unroll
    for (int ni = 0; ni < 8; ++ni)
      #pragma unroll
      for (int e = 0; e < 4; ++e) {
        const int row = g * 4 + e;
        const int col = ni * 16 + r;
        o_lds[w][row][col ^ ((row >> 2) << 3)] = o[ni][e];   // XOR-swizzle
      }
    __syncthreads();

    // ---- block-level additive reduce; write partial to workspace ----
    const int col = tid & 127;
    const size_t tile2 = ((size_t)(b * 128 + t)) * 2 + h;
    #pragma unroll
    for (int rr = 0; rr < 4; ++rr) {
      const int row = (tid >> 7) * 4 + rr;
      float val = 0.f;
      #pragma unroll
      for (int ww = 0; ww < 8; ++ww)
        val += o_lds[ww][row][col ^ ((row >> 2) << 3)];
      po[tile2 * 2048 + row * 128 + col] = val;
      if (col == 0) {
        float lt = 0.f;
        #pragma unroll
        for (int ww = 0; ww < 8; ++ww) lt += l_lds[ww][row];
        pl[tile2 * 16 + row] = lt;
      }
    }
    __syncthreads();   // protect o_lds/l_lds before next phase reuses them
  }
}

// ---- merge the two half-partials: out = (o0+o1)/(l0+l1) ----
__global__ __launch_bounds__(256) void combine(const float* __restrict__ po,
                                               const float* __restrict__ pl,
                                               float* __restrict__ out) {
  const int idx = blockIdx.x * 256 + threadIdx.x;   // [0, 1048576)
  const int col = idx & 127;
  const int gq = idx >> 7;          // [0, 8192)
  const int b = gq >> 11, q = gq & 2047;
  const int t = q >> 4, row = q & 15;
  const size_t tile2 = ((size_t)(b * 128 + t)) * 2;
  const float o = po[tile2 * 2048 + row * 128 + col] +
                  po[(tile2 + 1) * 2048 + row * 128 + col];
  const float l = pl[tile2 * 16 + row] + pl[(tile2 + 1) * 16 + row];
  out[idx] = (l > 0.f) ? o / l : 0.f;
}

// ---- last row (q = S-1): reference's score-1e9 rounds all-equal -> uniform softmax -> mean(V) ----
__global__ __launch_bounds__(64) void lastrow(const unsigned short* __restrict__ Vt,
                                              float* __restrict__ out) {
  const int b = blockIdx.x >> 7;
  const int dk = blockIdx.x & 127;
  const unsigned short* row = Vt + (size_t)(b * 128 + dk) * 2048;
  float s = 0.f;
  for (int i = threadIdx.x; i < 2048; i += 64) s += bf2f(row[i]);
  #pragma unroll
  for (int off = 32; off > 0; off >>= 1) s += __shfl_down(s, off, 64);
  if (threadIdx.x == 0) out[(size_t)(b * 2048 + 2047) * 128 + dk] = s * (1.0f / 2048.0f);
}

extern "C" void kernel_launch(void* const* d_in, const int* in_sizes, int n_in,
                              void* d_out, int out_size, void* d_ws, size_t ws_size,
                              hipStream_t stream) {
  const float* x  = (const float*)d_in[0];
  const float* Wq = (const float*)d_in[1];
  const float* bq = (const float*)d_in[2];
  const float* Wk = (const float*)d_in[3];
  const float* bk = (const float*)d_in[4];
  const float* Wv = (const float*)d_in[5];
  const float* bv = (const float*)d_in[6];
  float* out = (float*)d_out;
  char* ws = (char*)d_ws;
  // workspace layout (bytes):
  //   [0,16MB):  Xb (bf16 input)  -- dead after proj_gemm; po (8MB) + pl (64KB)
  //              alias this region (attn writes them AFTER proj_gemm consumed Xb)
  //   [16,17MB): Wt | [17,19): Qb | [19,21): Kb | [21,23): Vt
  unsigned short* Xb = (unsigned short*)(ws);
  float* po = (float*)(ws);
  float* pl = (float*)(ws + (size_t)(8u << 20));
  unsigned short* Wt = (unsigned short*)(ws + (size_t)(16u << 20));
  unsigned short* Qb = (unsigned short*)(ws + (size_t)(17u << 20));
  unsigned short* Kb = (unsigned short*)(ws + (size_t)(19u << 20));
  unsigned short* Vt = (unsigned short*)(ws + (size_t)(21u << 20));

  hipLaunchKernelGGL(cvt_x, dim3(4096), dim3(256), 0, stream, x, Xb);
  hipLaunchKernelGGL(cvt_w, dim3(1536), dim3(256), 0, stream, Wq, Wk, Wv, Wt);
  hipLaunchKernelGGL(proj_gemm, dim3(768), dim3(256), 0, stream,
                     Xb, Wt, bq, bk, bv, Qb, Kb, Vt);
  hipLaunchKernelGGL(attn, dim3(512), dim3(512), 0, stream, Qb, Kb, Vt, po, pl);
  hipLaunchKernelGGL(combine, dim3(4096), dim3(256), 0, stream, po, pl, out);
  hipLaunchKernelGGL(lastrow, dim3(512), dim3(64), 0, stream, Vt, out);
}

// Round 16
// 71.827 us; speedup vs baseline: 1.3856x; 1.2399x over previous
//
#include <hip/hip_runtime.h>
#include <hip/hip_bf16.h>

typedef __attribute__((ext_vector_type(8))) short bf16x8;
typedef __attribute__((ext_vector_type(4))) float f32x4;

#define QSCALE 0.088388347648318447f   /* 1/sqrt(128) */

__device__ __forceinline__ unsigned short f2bf(float f) {
  __hip_bfloat16 h = __float2bfloat16(f);
  unsigned short u;
  __builtin_memcpy(&u, &h, 2);
  return u;
}
__device__ __forceinline__ float bf2f(unsigned short u) {
  unsigned int x = ((unsigned int)u) << 16;
  float f; __builtin_memcpy(&f, &x, 4);
  return f;
}

__device__ __forceinline__ void gload_lds16(void* lds, const void* g) {
  __builtin_amdgcn_global_load_lds(
      (const __attribute__((address_space(1))) unsigned int*)g,
      (__attribute__((address_space(3))) unsigned int*)lds, 16, 0, 0);
}

// ---- convert inputs fp32 -> bf16 (8 elem/thread) ----
__global__ __launch_bounds__(256) void cvt_x(const float* __restrict__ x,
                                             unsigned short* __restrict__ xb) {
  int i = (blockIdx.x * 256 + threadIdx.x) * 8;
  float4 v0 = *reinterpret_cast<const float4*>(x + i);
  float4 v1 = *reinterpret_cast<const float4*>(x + i + 4);
  ushort4 o0, o1;
  o0.x = f2bf(v0.x); o0.y = f2bf(v0.y); o0.z = f2bf(v0.z); o0.w = f2bf(v0.w);
  o1.x = f2bf(v1.x); o1.y = f2bf(v1.y); o1.z = f2bf(v1.z); o1.w = f2bf(v1.w);
  *reinterpret_cast<ushort4*>(xb + i) = o0;
  *reinterpret_cast<ushort4*>(xb + i + 4) = o1;
}

// ---- build W^T (384 x 1024) bf16, Q part pre-scaled by 1/sqrt(dk) ----
__global__ __launch_bounds__(256) void cvt_w(const float* __restrict__ Wq,
                                             const float* __restrict__ Wk,
                                             const float* __restrict__ Wv,
                                             unsigned short* __restrict__ Wt) {
  int idx = blockIdx.x * 256 + threadIdx.x;   // [0, 393216)
  int n = idx >> 10, d = idx & 1023;
  const float* W = (n < 128) ? Wq : (n < 256 ? Wk : Wv);
  float v = W[d * 128 + (n & 127)];
  if (n < 128) v *= QSCALE;
  Wt[idx] = f2bf(v);
}

// ---- fused QKV projection: [8192x1024] @ [1024x384], 64x64 tiles ----
__global__ __launch_bounds__(256) void proj_gemm(
    const unsigned short* __restrict__ Xb, const unsigned short* __restrict__ Wt,
    const float* __restrict__ bq, const float* __restrict__ bk, const float* __restrict__ bv,
    unsigned short* __restrict__ Qb, unsigned short* __restrict__ Kb,
    unsigned short* __restrict__ Vt) {
  __shared__ unsigned short sA[64 * 64];
  __shared__ unsigned short sB[64 * 64];
  const int nt = blockIdx.x % 6;
  const int mt = blockIdx.x / 6;
  const int m0 = mt * 64;
  const int n0 = nt * 64;
  const int tid = threadIdx.x;
  const int lane = tid & 63;
  const int w = tid >> 6;
  const int r = lane & 15, g = lane >> 4;
  const int wm = (w >> 1) * 32, wn = (w & 1) * 32;

  f32x4 acc[2][2];
  #pragma unroll
  for (int mi = 0; mi < 2; ++mi)
    #pragma unroll
    for (int ni = 0; ni < 2; ++ni)
      acc[mi][ni] = (f32x4){0.f, 0.f, 0.f, 0.f};

  const char* Ab = (const char*)Xb;
  const char* Bb = (const char*)Wt;
  char* sAb = (char*)sA;
  char* sBb = (char*)sB;

  for (int k0 = 0; k0 < 1024; k0 += 64) {
    #pragma unroll
    for (int j = 0; j < 2; ++j) {
      int f = j * 4096 + tid * 16;   // byte offset within 8KB tile
      int row = f >> 7;              // 128 bytes per row (64 bf16)
      int colb = f & 127;
      gload_lds16(sAb + f, Ab + ((size_t)(m0 + row) * 1024 + k0) * 2 + colb);
      gload_lds16(sBb + f, Bb + ((size_t)(n0 + row) * 1024 + k0) * 2 + colb);
    }
    __syncthreads();
    #pragma unroll
    for (int kk = 0; kk < 2; ++kk) {
      bf16x8 af[2], bfr[2];
      #pragma unroll
      for (int mi = 0; mi < 2; ++mi)
        af[mi] = *reinterpret_cast<const bf16x8*>(sA + (wm + mi * 16 + r) * 64 + kk * 32 + g * 8);
      #pragma unroll
      for (int ni = 0; ni < 2; ++ni)
        bfr[ni] = *reinterpret_cast<const bf16x8*>(sB + (wn + ni * 16 + r) * 64 + kk * 32 + g * 8);
      #pragma unroll
      for (int mi = 0; mi < 2; ++mi)
        #pragma unroll
        for (int ni = 0; ni < 2; ++ni)
          acc[mi][ni] = __builtin_amdgcn_mfma_f32_16x16x32_bf16(af[mi], bfr[ni], acc[mi][ni], 0, 0, 0);
    }
    __syncthreads();
  }

  const float* bias = (nt < 2) ? bq : (nt < 4 ? bk : bv);
  const float bsc = (nt < 2) ? QSCALE : 1.0f;
  #pragma unroll
  for (int mi = 0; mi < 2; ++mi) {
    #pragma unroll
    for (int ni = 0; ni < 2; ++ni) {
      const int colg = n0 + wn + ni * 16 + r;      // [0,384)
      const int colm = colg & 127;
      const float bias_v = bias[colm] * bsc;
      #pragma unroll
      for (int e = 0; e < 4; ++e) {
        const int row = m0 + wm + mi * 16 + g * 4 + e;   // [0,8192)
        const unsigned short hh = f2bf(acc[mi][ni][e] + bias_v);
        if (nt < 2) Qb[(size_t)row * 128 + colm] = hh;
        else if (nt < 4) Kb[(size_t)row * 128 + colm] = hh;
        else {
          const int bb = row >> 11, s = row & 2047;
          Vt[((size_t)bb * 128 + colm) * 2048 + s] = hh;
        }
      }
    }
  }
}

// ---- flash attention: block-shared LDS-staged K/V, s-eighth split ----
// Block = (b, pair p, sigma): 128 q-rows (8 waves x 16), tiles j == sigma
// (mod 8); phases t=p / t=15-p (balance). Per s-tile the block stages K
// (8KB) and V (8KB) once via global_load_lds (XOR-swizzled source, rule #21),
// double-buffered, counted vmcnt(2) + raw s_barrier. 8 waves share the tile
// -> 8x L2-traffic cut (266->33MB; R14: attn pinned at ~6.3TB/s L2 BW).
// RACE FIX (R15): lgkmcnt(0)+sched_barrier BEFORE the trailing s_barrier —
// a wave's in-flight ds_reads must complete before it signals that the
// buffer may be overwritten (rule #18: MFMA+its waitcnt can hoist past
// "memory" asm, leaving reads pending at the barrier).
__global__ __launch_bounds__(512, 4) void attn(
    const unsigned short* __restrict__ Qb, const unsigned short* __restrict__ Kb,
    const unsigned short* __restrict__ Vt,
    float* __restrict__ po, float* __restrict__ pl) {
  __shared__ char sK[2][8192];
  __shared__ char sV[2][8192];
  __shared__ unsigned short pbuf_s[8][512];
  const int tid = threadIdx.x;
  const int lane = tid & 63;
  const int w = tid >> 6;
  const int r = lane & 15, g = lane >> 4;
  const int sig = blockIdx.x & 7;
  const int b = (blockIdx.x >> 3) & 3;
  const int p = blockIdx.x >> 5;            // [0,8)

  const char* Kg = (const char*)(Kb + (size_t)b * 2048 * 128);
  const char* Vg = (const char*)(Vt + (size_t)b * 128 * 2048);
  unsigned short* pbuf = pbuf_s[w];

  // staging address components (thread-constant)
  const int krow = tid >> 4;                         // [0,32)
  const int kcol = ((tid & 15) * 16) ^ ((krow & 7) * 16);
  const int vrow = tid >> 2;                         // [0,128)
  const int vcol = ((tid & 3) * 16) ^ ((vrow & 3) * 16);

  for (int phase = 0; phase < 2; ++phase) {
    const int t = phase ? (15 - p) : p;
    const int q0b = t << 7;                 // block q base (128-row tile)
    const int ntiles = (2048 - q0b) >> 5;   // 64 - 4t
    const int q0w = q0b + w * 16;

    const unsigned short* Q = Qb + (size_t)(b * 2048 + q0w) * 128;
    bf16x8 qf[4];
    #pragma unroll
    for (int kk = 0; kk < 4; ++kk)
      qf[kk] = *reinterpret_cast<const bf16x8*>(Q + r * 128 + kk * 32 + g * 8);

    f32x4 o[8];
    #pragma unroll
    for (int ni = 0; ni < 8; ++ni) o[ni] = (f32x4){0.f, 0.f, 0.f, 0.f};
    float l[4];
    #pragma unroll
    for (int e = 0; e < 4; ++e) l[e] = 0.f;

    const int nT = (ntiles > sig) ? ((ntiles - sig + 7) >> 3) : 0;  // block-uniform

    if (nT > 0) {
      const int s0 = q0b + (sig << 5);
      gload_lds16(&sK[0][tid * 16], Kg + (size_t)(s0 + krow) * 256 + kcol);
      gload_lds16(&sV[0][tid * 16], Vg + (size_t)vrow * 4096 + (size_t)s0 * 2 + vcol);
    }
    for (int it = 0; it < nT; ++it) {
      const int cur = it & 1;
      const int s0 = q0b + ((sig + (it << 3)) << 5);
      if (it + 1 < nT) {
        const int s1 = s0 + 256;
        gload_lds16(&sK[cur ^ 1][tid * 16], Kg + (size_t)(s1 + krow) * 256 + kcol);
        gload_lds16(&sV[cur ^ 1][tid * 16], Vg + (size_t)vrow * 4096 + (size_t)s1 * 2 + vcol);
        asm volatile("s_waitcnt vmcnt(2)" ::: "memory");
      } else {
        asm volatile("s_waitcnt vmcnt(0)" ::: "memory");
      }
      asm volatile("s_barrier" ::: "memory");   // staged tile ready for all waves

      // ---- QK^T from LDS (swizzled reads, 2-way max) ----
      f32x4 st[2];
      #pragma unroll
      for (int sj = 0; sj < 2; ++sj) {
        f32x4 a = (f32x4){0.f, 0.f, 0.f, 0.f};
        #pragma unroll
        for (int kk = 0; kk < 4; ++kk) {
          const bf16x8 kf = *reinterpret_cast<const bf16x8*>(
              &sK[cur][(sj * 16 + r) * 256 + (((kk * 64 + g * 16) ^ ((r & 7) * 16)))]);
          a = __builtin_amdgcn_mfma_f32_16x16x32_bf16(qf[kk], kf, a, 0, 0, 0);
        }
        st[sj] = a;
      }
      // mask (valid iff s > q) + exp(fixed max 0); defer row-sum butterfly
      #pragma unroll
      for (int sj = 0; sj < 2; ++sj) {
        const int s = s0 + sj * 16 + r;
        #pragma unroll
        for (int e = 0; e < 4; ++e) {
          const int q = q0w + g * 4 + e;
          st[sj][e] = (s <= q) ? 0.f : __expf(st[sj][e]);
        }
      }
      #pragma unroll
      for (int e = 0; e < 4; ++e) l[e] += st[0][e] + st[1][e];

      // transpose P through per-wave LDS: [q_local][s_local] bf16
      #pragma unroll
      for (int sj = 0; sj < 2; ++sj)
        #pragma unroll
        for (int e = 0; e < 4; ++e)
          pbuf[(g * 4 + e) * 32 + sj * 16 + r] = f2bf(st[sj][e]);
      asm volatile("s_waitcnt lgkmcnt(0)" ::: "memory");
      __builtin_amdgcn_sched_barrier(0);
      const bf16x8 pa = *reinterpret_cast<const bf16x8*>(&pbuf[r * 32 + g * 8]);

      // ---- P.V from LDS (swizzled reads, 4-way max) ----
      #pragma unroll
      for (int ni = 0; ni < 8; ++ni) {
        const bf16x8 vf = *reinterpret_cast<const bf16x8*>(
            &sV[cur][(ni * 16 + r) * 64 + ((g * 16) ^ ((r & 3) * 16))]);
        o[ni] = __builtin_amdgcn_mfma_f32_16x16x32_bf16(pa, vf, o[ni], 0, 0, 0);
      }
      // RACE FIX: drain this wave's LDS reads before signaling reuse-safe.
      asm volatile("s_waitcnt lgkmcnt(0)" ::: "memory");
      __builtin_amdgcn_sched_barrier(0);
      asm volatile("s_barrier" ::: "memory");   // all reads done -> next overwrite safe
    }

    // ---- deferred row-sum butterfly (once per phase) ----
    #pragma unroll
    for (int off = 1; off < 16; off <<= 1)
      #pragma unroll
      for (int e = 0; e < 4; ++e)
        l[e] += __shfl_xor(l[e], off, 64);

    // ---- epilogue: wave-private partial write (no block reduce) ----
    const size_t pb = ((size_t)((b * 16 + t) * 8 + sig)) * 16384;
    #pragma unroll
    for (int ni = 0; ni < 8; ++ni)
      #pragma unroll
      for (int e = 0; e < 4; ++e)
        po[pb + (size_t)(w * 16 + g * 4 + e) * 128 + ni * 16 + r] = o[ni][e];
    if (r == 0) {
      #pragma unroll
      for (int e = 0; e < 4; ++e)
        pl[((size_t)((b * 16 + t) * 8 + sig)) * 128 + w * 16 + g * 4 + e] = l[e];
    }
  }
}

// ---- merge the eight sigma-partials: out = sum(o)/sum(l) ----
__global__ __launch_bounds__(256) void combine(const float* __restrict__ po,
                                               const float* __restrict__ pl,
                                               float* __restrict__ out) {
  const int idx = blockIdx.x * 256 + threadIdx.x;   // [0, 1048576)
  const int d = idx & 127;
  const int gq = idx >> 7;          // [0, 8192)
  const int b = gq >> 11, q = gq & 2047;
  const int qt = q >> 7, row = q & 127;
  const size_t base = (size_t)(b * 16 + qt) * 8;
  float o = 0.f, l = 0.f;
  #pragma unroll
  for (int s = 0; s < 8; ++s) {
    o += po[(base + s) * 16384 + row * 128 + d];
    l += pl[(base + s) * 128 + row];
  }
  out[idx] = (l > 0.f) ? o / l : 0.f;
}

// ---- last row (q = S-1): reference's score-1e9 rounds all-equal -> uniform softmax -> mean(V) ----
__global__ __launch_bounds__(64) void lastrow(const unsigned short* __restrict__ Vt,
                                              float* __restrict__ out) {
  const int b = blockIdx.x >> 7;
  const int dk = blockIdx.x & 127;
  const unsigned short* row = Vt + (size_t)(b * 128 + dk) * 2048;
  float s = 0.f;
  for (int i = threadIdx.x; i < 2048; i += 64) s += bf2f(row[i]);
  #pragma unroll
  for (int off = 32; off > 0; off >>= 1) s += __shfl_down(s, off, 64);
  if (threadIdx.x == 0) out[(size_t)(b * 2048 + 2047) * 128 + dk] = s * (1.0f / 2048.0f);
}

extern "C" void kernel_launch(void* const* d_in, const int* in_sizes, int n_in,
                              void* d_out, int out_size, void* d_ws, size_t ws_size,
                              hipStream_t stream) {
  const float* x  = (const float*)d_in[0];
  const float* Wq = (const float*)d_in[1];
  const float* bq = (const float*)d_in[2];
  const float* Wk = (const float*)d_in[3];
  const float* bk = (const float*)d_in[4];
  const float* Wv = (const float*)d_in[5];
  const float* bv = (const float*)d_in[6];
  float* out = (float*)d_out;
  char* ws = (char*)d_ws;
  // workspace layout (bytes), no aliasing:
  //   [0,16MB): Xb | [16,17): Wt | [17,19): Qb | [19,21): Kb | [21,23): Vt
  //   [24,56MB): po (4x16x8 x 128x128 fp32) | [56MB,+64KB): pl
  unsigned short* Xb = (unsigned short*)(ws);
  unsigned short* Wt = (unsigned short*)(ws + (size_t)(16u << 20));
  unsigned short* Qb = (unsigned short*)(ws + (size_t)(17u << 20));
  unsigned short* Kb = (unsigned short*)(ws + (size_t)(19u << 20));
  unsigned short* Vt = (unsigned short*)(ws + (size_t)(21u << 20));
  float* po = (float*)(ws + (size_t)(24u << 20));
  float* pl = (float*)(ws + (size_t)(56u << 20));

  hipLaunchKernelGGL(cvt_x, dim3(4096), dim3(256), 0, stream, x, Xb);
  hipLaunchKernelGGL(cvt_w, dim3(1536), dim3(256), 0, stream, Wq, Wk, Wv, Wt);
  hipLaunchKernelGGL(proj_gemm, dim3(768), dim3(256), 0, stream,
                     Xb, Wt, bq, bk, bv, Qb, Kb, Vt);
  hipLaunchKernelGGL(attn, dim3(256), dim3(512), 0, stream, Qb, Kb, Vt, po, pl);
  hipLaunchKernelGGL(combine, dim3(4096), dim3(256), 0, stream, po, pl, out);
  hipLaunchKernelGGL(lastrow, dim3(512), dim3(64), 0, stream, Vt, out);
}